// Round 14
// baseline (93807.294 us; speedup 1.0000x reference)
//
#include <hip/hip_runtime.h>
#include <math.h>

#define FIN   32
#define HH    512
#define G4    2048
#define BNE   64
#define OUTD  8
#define SEQL  128
#define LOOK  32
#define TOT   (SEQL + LOOK)
#define GS    32              // samples per 4-WG group
#define NTHR  1024
#define NWG   256

// ---- workspace layout (float indices) — r10 verbatim ----
#define ST_SZ   (64 * HH * GS)
#define WS_ST   1024
#define WS_H0D  (WS_ST + 4 * ST_SZ)
#define WS_H1D  (WS_H0D + ST_SZ)
#define WS_TR   (WS_H1D + ST_SZ)
#define WS_SOUT (WS_TR + 64 * 2 * BNE * GS)

__device__ __forceinline__ float sigf(float v) { return 1.0f / (1.0f + expf(-v)); }

// coherence-point (system-scope, relaxed) accessors: no cache flushes anywhere
__device__ __forceinline__ float ldx(const float* p) {
  return __hip_atomic_load(p, __ATOMIC_RELAXED, __HIP_MEMORY_SCOPE_SYSTEM);
}
__device__ __forceinline__ void stx(float* p, float v) {
  __hip_atomic_store(p, v, __ATOMIC_RELAXED, __HIP_MEMORY_SCOPE_SYSTEM);
}

// 4-WG group barrier: RELAXED atomics only. Ordering: __syncthreads drains
// vmcnt before s_barrier, so all data stores precede the flag add; consumer
// reads via coherence-point loads after the flag. NO threadfence (no L2 nuke).
__device__ __forceinline__ void gbar(int* cnt, int target) {
  __syncthreads();
  if (threadIdx.x == 0) {
    asm volatile("s_waitcnt vmcnt(0)" ::: "memory");
    __hip_atomic_fetch_add(cnt, 1, __ATOMIC_RELAXED, __HIP_MEMORY_SCOPE_SYSTEM);
    while (__hip_atomic_load(cnt, __ATOMIC_RELAXED, __HIP_MEMORY_SCOPE_SYSTEM) < target)
      __builtin_amdgcn_s_sleep(4);
  }
  __syncthreads();
}

// r10-verbatim MAC
#define MACQ(HA, HB)                                            \
  { a[0].x = fmaf(w.x, HA.x, a[0].x); a[0].y = fmaf(w.y, HA.x, a[0].y); \
    a[1].x = fmaf(w.x, HA.y, a[1].x); a[1].y = fmaf(w.y, HA.y, a[1].y); \
    a[2].x = fmaf(w.x, HA.z, a[2].x); a[2].y = fmaf(w.y, HA.z, a[2].y); \
    a[3].x = fmaf(w.x, HA.w, a[3].x); a[3].y = fmaf(w.y, HA.w, a[3].y); \
    a[4].x = fmaf(w.x, HB.x, a[4].x); a[4].y = fmaf(w.y, HB.x, a[4].y); \
    a[5].x = fmaf(w.x, HB.y, a[5].x); a[5].y = fmaf(w.y, HB.y, a[5].y); \
    a[6].x = fmaf(w.x, HB.z, a[6].x); a[6].y = fmaf(w.y, HB.z, a[6].y); \
    a[7].x = fmaf(w.x, HB.w, a[7].x); a[7].y = fmaf(w.y, HB.w, a[7].y); }

__global__ __launch_bounds__(NTHR)
void fused_rnn(const float* __restrict__ x,
               const float* __restrict__ Wih0, const float* __restrict__ Whh0,
               const float* __restrict__ bih0, const float* __restrict__ bhh0,
               const float* __restrict__ Wih1, const float* __restrict__ Whh1,
               const float* __restrict__ bih1, const float* __restrict__ bhh1,
               const float* __restrict__ We,   const float* __restrict__ be,
               const float* __restrict__ Wd,   const float* __restrict__ bd,
               const float* __restrict__ Wf,   const float* __restrict__ bf,
               float* __restrict__ out, float* __restrict__ ws)
{
  __shared__ float arena[HH * GS];        // 64 KB time-shared
  __shared__ float tq[2][BNE][GS];        // 16 KB trits; sxT overlay in P3
  __shared__ float cd[2][128][GS + 1];    // 33 KB decoded-c quarters

#define AK(K, S) arena[(K) * GS + (S)]
#define GB(S, C) arena[(S) * HH + (C)]

  const int t    = threadIdx.x;
  const int bid  = blockIdx.x;
  // XCD-local grouping: members of a group share bid%8 (same XCD under
  // round-robin dispatch) -> weight-quarter reuse in that XCD's L2.
  const int xcd  = bid & 7;
  const int slot = bid >> 3;              // 0..31 within XCD
  const int Q    = slot & 3;              // quarter 0..3
  const int G    = xcd * 8 + (slot >> 2); // group 0..63
  const int S0   = G * GS;
  const int UQ   = Q * 128;

  int*   cnt = (int*)ws + G * 16;
  float* h0c = ws + WS_ST + 0 * ST_SZ + G * (HH * GS);
  float* c0c = ws + WS_ST + 1 * ST_SZ + G * (HH * GS);
  float* h1c = ws + WS_ST + 2 * ST_SZ + G * (HH * GS);
  float* c1c = ws + WS_ST + 3 * ST_SZ + G * (HH * GS);
  float* h0d = ws + WS_H0D + G * (HH * GS);
  float* h1d = ws + WS_H1D + G * (HH * GS);
  float* trg = ws + WS_TR  + G * (2 * BNE * GS);
  float* sog = ws + WS_SOUT + G * (GS * OUTD);

  // r10-verbatim mappings
  const int u = t & 255, v = t >> 8;
  const int p = u >> 6, wl = u & 63;
  const int cg = p * HH + UQ + 2 * wl;
  const float2 bb0 = make_float2(bih0[cg] + bhh0[cg], bih0[cg + 1] + bhh0[cg + 1]);
  const float2 bb1 = make_float2(bih1[cg] + bhh1[cg], bih1[cg + 1] + bhh1[cg + 1]);

  const int cl = t & 255, sg2 = t >> 8;
  const int dcol = (cl < 128) ? (UQ + cl) : (HH + UQ + (cl - 128));
  const float bdv = bd[dcol];

  const int ae = t >> 9, se = (t >> 6) & 7, n = t & 63;
  const int sE = 8 * Q + se;

  const int ul = t & 127, sq8 = t >> 7;

  const double Athr = 0.5493061443340549;

  int bar = 0;

  for (int step = 0; step < TOT; ++step) {
    // ============ P1: stage own-Q state slices -> arena; AE encoders (fp64) ========
    {
#pragma unroll
      for (int i = 0; i < 2; i++) {
        const int pp = 2 * t + i, k = pp >> 2, aidx = pp & 3;
        const float* src = (aidx == 0) ? h0c : (aidx == 1) ? c0c
                         : (aidx == 2) ? h1c : c1c;
        const float* sp = src + (size_t)k * GS + 8 * Q;
        float* dp = &AK(k, aidx * 8);
#pragma unroll
        for (int j = 0; j < 8; j++) dp[j] = ldx(sp + j);
      }
      __syncthreads();
      double a0 = (double)be[n];
      const float* weh = We + n;
#pragma unroll 4
      for (int k = 0; k < HH; k++)
        a0 = fma((double)AK(k, 16 * ae + se), (double)weh[(size_t)k * BNE], a0);
      const float* wec = We + (size_t)HH * BNE + n;
#pragma unroll 4
      for (int k = 0; k < HH; k++)
        a0 = fma((double)AK(k, 16 * ae + 8 + se), (double)wec[(size_t)k * BNE], a0);
      stx(&trg[ae * (BNE * GS) + n * GS + sE],
          (a0 > Athr) ? 1.f : ((a0 < -Athr) ? -1.f : 0.f));
    }
    gbar(cnt, 4 * (++bar));

    // ============ P2: AE decode (column quarter, both AEs) — r10 chains ============
    {
      for (int i = t; i < 2 * BNE * GS; i += NTHR) (&tq[0][0][0])[i] = ldx(trg + i);
      __syncthreads();
      float ac0[8], ac1[8];
#pragma unroll
      for (int s = 0; s < 8; s++) { ac0[s] = bdv; ac1[s] = bdv; }
      const float* wd = Wd + dcol;
#pragma unroll 2
      for (int j = 0; j < BNE; j++) {
        const float wv = wd[(size_t)j * (2 * HH)];
        const float4 qA0 = *(const float4*)&tq[0][j][8 * sg2];
        const float4 qB0 = *(const float4*)&tq[0][j][8 * sg2 + 4];
        const float4 qA1 = *(const float4*)&tq[1][j][8 * sg2];
        const float4 qB1 = *(const float4*)&tq[1][j][8 * sg2 + 4];
        ac0[0] = fmaf(qA0.x, wv, ac0[0]); ac0[1] = fmaf(qA0.y, wv, ac0[1]);
        ac0[2] = fmaf(qA0.z, wv, ac0[2]); ac0[3] = fmaf(qA0.w, wv, ac0[3]);
        ac0[4] = fmaf(qB0.x, wv, ac0[4]); ac0[5] = fmaf(qB0.y, wv, ac0[5]);
        ac0[6] = fmaf(qB0.z, wv, ac0[6]); ac0[7] = fmaf(qB0.w, wv, ac0[7]);
        ac1[0] = fmaf(qA1.x, wv, ac1[0]); ac1[1] = fmaf(qA1.y, wv, ac1[1]);
        ac1[2] = fmaf(qA1.z, wv, ac1[2]); ac1[3] = fmaf(qA1.w, wv, ac1[3]);
        ac1[4] = fmaf(qB1.x, wv, ac1[4]); ac1[5] = fmaf(qB1.y, wv, ac1[5]);
        ac1[6] = fmaf(qB1.z, wv, ac1[6]); ac1[7] = fmaf(qB1.w, wv, ac1[7]);
      }
      if (cl < 128) {
        float* p0 = h0d + (size_t)(UQ + cl) * GS + 8 * sg2;
        float* p1 = h1d + (size_t)(UQ + cl) * GS + 8 * sg2;
#pragma unroll
        for (int s = 0; s < 8; s++) { stx(p0 + s, ac0[s]); stx(p1 + s, ac1[s]); }
      } else {
#pragma unroll
        for (int s = 0; s < 8; s++) {
          cd[0][cl - 128][8 * sg2 + s] = ac0[s];
          cd[1][cl - 128][8 * sg2 + s] = ac1[s];
        }
      }
    }
    gbar(cnt, 4 * (++bar));

    // ============ P3: layer-0 LSTM (quarter cols; states staged to LDS) ============
    {
      float* sxT = &tq[0][0][0];
      { int s = t >> 5, f = t & 31;
        float xv;
        if (step >= SEQL && f < OUTD) xv = ldx(&sog[s * OUTD + f]);
        else xv = x[((size_t)(S0 + s) * TOT + step) * FIN + f];
        sxT[f * GS + s] = xv; }
      for (int i = t; i < HH * GS; i += NTHR) arena[i] = ldx(h0d + i);
      __syncthreads();

      float2 a[8];
#pragma unroll
      for (int s = 0; s < 8; s++) a[s] = bb0;
      const float2* wx = (const float2*)(Wih0 + cg);
#pragma unroll 4
      for (int k = 0; k < FIN; k++) {
        const float2 w  = wx[(size_t)k * (G4 / 2)];
        const float4 hA = *(const float4*)&sxT[k * GS + 8 * v];
        const float4 hB = *(const float4*)&sxT[k * GS + 8 * v + 4];
        MACQ(hA, hB);
      }
      const float2* wh = (const float2*)(Whh0 + cg);
#pragma unroll 8
      for (int k = 0; k < HH; k++) {
        const float2 w  = wh[(size_t)k * (G4 / 2)];
        const float4 hA = *(const float4*)&AK(k, 8 * v);
        const float4 hB = *(const float4*)&AK(k, 8 * v + 4);
        MACQ(hA, hB);
      }
      __syncthreads();   // arena (h0d) dead -> gate buffer
#pragma unroll
      for (int s = 0; s < 8; s++)
        *(float2*)&GB(8 * v + s, p * 128 + 2 * wl) = a[s];
      __syncthreads();
#pragma unroll
      for (int i = 0; i < 4; i++) {
        const int s = sq8 * 4 + i;
        const float ig = sigf(GB(s, ul));
        const float fg = sigf(GB(s, 128 + ul));
        const float gt = tanhf(GB(s, 256 + ul));
        const float og = sigf(GB(s, 384 + ul));
        const float c2 = fmaf(fg, cd[0][ul][s], ig * gt);
        stx(&h0c[(UQ + ul) * GS + s], og * tanhf(c2));
        stx(&c0c[(UQ + ul) * GS + s], c2);
      }
    }
    gbar(cnt, 4 * (++bar));

    // ============ P4: layer-1 LSTM (staged h0c, then staged h1d) ============
    {
      for (int i = t; i < HH * GS; i += NTHR) arena[i] = ldx(h0c + i);
      __syncthreads();
      float2 a[8];
#pragma unroll
      for (int s = 0; s < 8; s++) a[s] = bb1;
      const float2* wx = (const float2*)(Wih1 + cg);
#pragma unroll 8
      for (int k = 0; k < HH; k++) {
        const float2 w  = wx[(size_t)k * (G4 / 2)];
        const float4 hA = *(const float4*)&AK(k, 8 * v);
        const float4 hB = *(const float4*)&AK(k, 8 * v + 4);
        MACQ(hA, hB);
      }
      __syncthreads();   // arena (h0c) dead
      for (int i = t; i < HH * GS; i += NTHR) arena[i] = ldx(h1d + i);
      __syncthreads();
      const float2* wh = (const float2*)(Whh1 + cg);
#pragma unroll 8
      for (int k = 0; k < HH; k++) {
        const float2 w  = wh[(size_t)k * (G4 / 2)];
        const float4 hA = *(const float4*)&AK(k, 8 * v);
        const float4 hB = *(const float4*)&AK(k, 8 * v + 4);
        MACQ(hA, hB);
      }
      __syncthreads();   // arena (h1d) dead -> gate buffer
#pragma unroll
      for (int s = 0; s < 8; s++)
        *(float2*)&GB(8 * v + s, p * 128 + 2 * wl) = a[s];
      __syncthreads();
#pragma unroll
      for (int i = 0; i < 4; i++) {
        const int s = sq8 * 4 + i;
        const float ig = sigf(GB(s, ul));
        const float fg = sigf(GB(s, 128 + ul));
        const float gt = tanhf(GB(s, 256 + ul));
        const float og = sigf(GB(s, 384 + ul));
        const float c2 = fmaf(fg, cd[1][ul][s], ig * gt);
        stx(&h1c[(UQ + ul) * GS + s], og * tanhf(c2));
        stx(&c1c[(UQ + ul) * GS + s], c2);
      }
    }
    gbar(cnt, 4 * (++bar));

    // ============ P5: final dense (h1c staged to LDS; own 8 samples) ============
    if (step >= SEQL - 1) {
      for (int i = t; i < HH * GS; i += NTHR) arena[i] = ldx(h1c + i);
      __syncthreads();
      if (t < 8 * OUTD) {
        const int s8 = t >> 3, o = t & 7;
        const int sl = 8 * Q + s8;
        float acc = bf[o];
#pragma unroll 4
        for (int k = 0; k < HH; k++)
          acc = fmaf(AK(k, sl), Wf[k * OUTD + o], acc);
        stx(&sog[sl * OUTD + o], acc);
        const int slot2 = step - (SEQL - 1);
        out[((size_t)(S0 + sl) * (1 + LOOK) + slot2) * OUTD + o] = acc;
      }
      __syncthreads();   // protect arena before next P1 restage
    }
  }
#undef AK
#undef GB
}

extern "C" void kernel_launch(void* const* d_in, const int* in_sizes, int n_in,
                              void* d_out, int out_size, void* d_ws, size_t ws_size,
                              hipStream_t stream) {
  const float* x    = (const float*)d_in[0];
  const float* Wih0 = (const float*)d_in[1];
  const float* Whh0 = (const float*)d_in[2];
  const float* bih0 = (const float*)d_in[3];
  const float* bhh0 = (const float*)d_in[4];
  const float* Wih1 = (const float*)d_in[5];
  const float* Whh1 = (const float*)d_in[6];
  const float* bih1 = (const float*)d_in[7];
  const float* bhh1 = (const float*)d_in[8];
  const float* We   = (const float*)d_in[9];
  const float* be   = (const float*)d_in[10];
  const float* Wd   = (const float*)d_in[11];
  const float* bd   = (const float*)d_in[12];
  const float* Wf   = (const float*)d_in[13];
  const float* bf   = (const float*)d_in[14];

  // zero group counters + initial states every launch
  hipMemsetAsync(d_ws, 0, (size_t)(WS_ST + 4 * ST_SZ) * sizeof(float), stream);

  fused_rnn<<<NWG, NTHR, 0, stream>>>(x, Wih0, Whh0, bih0, bhh0,
                                      Wih1, Whh1, bih1, bhh1,
                                      We, be, Wd, bd, Wf, bf,
                                      (float*)d_out, (float*)d_ws);
}